// Round 10
// baseline (39574.969 us; speedup 1.0000x reference)
//
#include <hip/hip_runtime.h>
#include <hip/hip_bf16.h>
#include <hip/hip_fp16.h>

#define NEGV (-1e30f)

constexpr int Bc = 64;    // batch == wave size
constexpr int Dc = 2048;  // pdf dim
constexpr int Tc = 150;   // time steps
constexpr int NBLK = 1024;  // persistent grid: 4 blocks/CU, must stay co-resident
constexpr float DRIFT = -5.0f;   // per-step drift guess; re-centering self-corrects
// Tight clamp so no-max exp accumulation cannot overflow:
// score = a + w + lp <= 40 + 0.5 + 0 = 40.5 ; exp(40.5)*13 ~ 5e18 << 3.4e38.
constexpr float CLAMP_LO = -60.0f, CLAMP_HI = 40.0f;

// ---- transpose input [T][B][D] f32 -> [T][D][B] fp16 ----
__global__ void transpose_kernel(const float* __restrict__ in, __half* __restrict__ out) {
    __shared__ float tile[64][65];
    const int t  = blockIdx.y;
    const int d0 = blockIdx.x * 64;
    const int lane = threadIdx.x & 63;
    const int w    = threadIdx.x >> 6;  // 0..3
    const float* inp = in + (size_t)t * Bc * Dc;
    #pragma unroll
    for (int b = w; b < 64; b += 4)
        tile[b][lane] = inp[(size_t)b * Dc + d0 + lane];
    __syncthreads();
    __half* outp = out + (size_t)t * Dc * Bc;
    #pragma unroll
    for (int d = w; d < 64; d += 4)
        outp[(size_t)(d0 + d) * Bc + lane] = __float2half(tile[lane][d]);
}

// ---- alpha_h[s][b] = init_logp[s] (fp16, clamped) ----
__global__ void init_alpha_kernel(const float* __restrict__ init_logp,
                                  __half* __restrict__ alpha_h, int S) {
    int idx  = blockIdx.x * blockDim.x + threadIdx.x;
    int wave = idx >> 6;
    int lane = threadIdx.x & 63;
    if (wave < S) {
        float v = fminf(fmaxf(init_logp[wave], CLAMP_LO), CLAMP_HI);
        alpha_h[(size_t)wave * Bc + lane] = __float2half(v);
    }
}

// ---- histogram of to_state ----
__global__ void hist_kernel(const int* __restrict__ to, int* __restrict__ count, int A) {
    int i = blockIdx.x * blockDim.x + threadIdx.x;
    if (i < A) atomicAdd(&count[to[i]], 1);
}

// ---- single-block exclusive scan -> row_ptr, cursor ----
__global__ void scan_kernel(const int* __restrict__ count, int* __restrict__ row_ptr,
                            int* __restrict__ cursor, int S) {
    __shared__ int lds[1024];
    const int tid = threadIdx.x;
    const int n = 1024;
    const int chunk = (S + n - 1) / n;
    const int lo = tid * chunk;
    const int hi = min(lo + chunk, S);
    int local = 0;
    for (int j = lo; j < hi; ++j) local += count[j];
    lds[tid] = local;
    __syncthreads();
    for (int off = 1; off < 1024; off <<= 1) {
        int add = (tid >= off) ? lds[tid - off] : 0;
        __syncthreads();
        lds[tid] += add;
        __syncthreads();
    }
    int excl = (tid > 0) ? lds[tid - 1] : 0;
    for (int j = lo; j < hi; ++j) {
        int c = count[j];
        row_ptr[j] = excl;
        cursor[j]  = excl;
        excl += c;
    }
    if (tid == n - 1) row_ptr[S] = lds[n - 1];
}

// ---- scatter arcs sorted by to_state, packed 8B: {f:u32, pdf:u16, w:fp16} ----
__global__ void scatter_kernel(const int* __restrict__ to, const int* __restrict__ from,
                               const int* __restrict__ pdf, const float* __restrict__ w,
                               int* __restrict__ cursor, uint2* __restrict__ a_pack, int A) {
    int i = blockIdx.x * blockDim.x + threadIdx.x;
    if (i >= A) return;
    int t = to[i];
    int p = atomicAdd(&cursor[t], 1);
    unsigned short wb = __half_as_ushort(__float2half(w[i]));
    a_pack[p] = make_uint2((unsigned)from[i],
                           ((unsigned)pdf[i] & 0xffffu) | ((unsigned)wb << 16));
}

// ---- device-scope grid barrier (sense-reversing, block-0 aggregator) ----
__device__ __forceinline__ void grid_barrier(int* __restrict__ arrival,
                                             int* __restrict__ gen,
                                             int nblk, int sense) {
    __syncthreads();
    __threadfence();  // release: push our writes to the coherence point (L3)
    if (blockIdx.x != 0) {
        if (threadIdx.x == 0) {
            __hip_atomic_store(&arrival[blockIdx.x - 1], sense,
                               __ATOMIC_RELEASE, __HIP_MEMORY_SCOPE_AGENT);
            while (__hip_atomic_load(gen, __ATOMIC_ACQUIRE,
                                     __HIP_MEMORY_SCOPE_AGENT) < sense)
                __builtin_amdgcn_s_sleep(4);
        }
    } else {
        for (int i = threadIdx.x; i < nblk - 1; i += 256) {
            while (__hip_atomic_load(&arrival[i], __ATOMIC_ACQUIRE,
                                     __HIP_MEMORY_SCOPE_AGENT) < sense)
                __builtin_amdgcn_s_sleep(4);
        }
        __syncthreads();
        if (threadIdx.x == 0)
            __hip_atomic_store(gen, sense, __ATOMIC_RELEASE,
                               __HIP_MEMORY_SCOPE_AGENT);
    }
    __syncthreads();
    __threadfence();  // acquire: invalidate stale L2 before reading remote data
}

// ---- persistent forward recursion: all T steps in one dispatch ----
__global__ __launch_bounds__(256, 4)
void persist_kernel(__half* __restrict__ alphaA, __half* __restrict__ alphaB,
                    float* __restrict__ off_out,
                    const __half* __restrict__ logpT,   // [T][D][B]
                    const int* __restrict__ row_ptr,
                    const uint2* __restrict__ arcs,
                    int S, int T,
                    int* __restrict__ arrival, int* __restrict__ gen) {
    const int gwave  = (blockIdx.x * blockDim.x + threadIdx.x) >> 6;
    const int lane   = threadIdx.x & 63;
    const int nwaves = (NBLK * 256) >> 6;   // 4096
    float offAcc = 0.0f;
    const __half* cur = alphaA;
    __half* nxt = alphaB;

    for (int t = 0; t < T; ++t) {
        const __half* lp = logpT + (size_t)t * Dc * Bc;
        // per-lane re-center reference from states 0..3 of cur (self-correcting)
        const float r0 = __half2float(cur[0 * Bc + lane]);
        const float r1 = __half2float(cur[1 * Bc + lane]);
        const float r2 = __half2float(cur[2 * Bc + lane]);
        const float r3 = __half2float(cur[3 * Bc + lane]);
        const float delta = fmaxf(fmaxf(r0, r1), fmaxf(r2, r3)) + DRIFT;

        for (int s = gwave; s < S; s += nwaves) {
            const int lo = __builtin_amdgcn_readfirstlane(row_ptr[s]);
            const int hi = __builtin_amdgcn_readfirstlane(row_ptr[s + 1]);
            float s0 = 0.0f, s1 = 0.0f, s2 = 0.0f, s3 = 0.0f;
            int i = lo;
            for (; i + 3 < hi; i += 4) {
                const uint2 A0 = arcs[i],     A1 = arcs[i + 1];
                const uint2 A2 = arcs[i + 2], A3 = arcs[i + 3];
                const float w0 = __half2float(__ushort_as_half((unsigned short)(A0.y >> 16)));
                const float w1 = __half2float(__ushort_as_half((unsigned short)(A1.y >> 16)));
                const float w2 = __half2float(__ushort_as_half((unsigned short)(A2.y >> 16)));
                const float w3 = __half2float(__ushort_as_half((unsigned short)(A3.y >> 16)));
                const float lp0 = __half2float(lp[(size_t)(A0.y & 0xffffu) * Bc + lane]);
                const float lp1 = __half2float(lp[(size_t)(A1.y & 0xffffu) * Bc + lane]);
                const float lp2 = __half2float(lp[(size_t)(A2.y & 0xffffu) * Bc + lane]);
                const float lp3 = __half2float(lp[(size_t)(A3.y & 0xffffu) * Bc + lane]);
                const float a0 = __half2float(cur[(size_t)A0.x * Bc + lane]);
                const float a1 = __half2float(cur[(size_t)A1.x * Bc + lane]);
                const float a2 = __half2float(cur[(size_t)A2.x * Bc + lane]);
                const float a3 = __half2float(cur[(size_t)A3.x * Bc + lane]);
                s0 += __expf(a0 + w0 + lp0);
                s1 += __expf(a1 + w1 + lp1);
                s2 += __expf(a2 + w2 + lp2);
                s3 += __expf(a3 + w3 + lp3);
            }
            for (; i < hi; ++i) {
                const uint2 A0 = arcs[i];
                const float w0 = __half2float(__ushort_as_half((unsigned short)(A0.y >> 16)));
                const float lp0 = __half2float(lp[(size_t)(A0.y & 0xffffu) * Bc + lane]);
                s0 += __expf(__half2float(cur[(size_t)A0.x * Bc + lane]) + w0 + lp0);
            }
            const float r = __logf(((s0 + s1) + (s2 + s3)) + 1e-30f);
            const float v = fminf(fmaxf(r - delta, CLAMP_LO), CLAMP_HI);
            nxt[(size_t)s * Bc + lane] = __float2half(v);
        }
        if (gwave == 0) offAcc += delta;
        grid_barrier(arrival, gen, NBLK, t + 1);
        const __half* tc = cur; cur = nxt; nxt = (__half*)tc;
    }
    if (gwave == 0) off_out[lane] = offAcc;
}

// ---- final: per-batch logsumexp(stored + final_logp) + OFF[b], atomicAdd ----
__global__ void final_reduce_kernel(const __half* __restrict__ alpha,
                                    const float* __restrict__ off,
                                    const float* __restrict__ final_logp,
                                    float* __restrict__ out, int S) {
    const int b = blockIdx.x;     // 0..B-1
    const int tid = threadIdx.x;  // 256
    float m = NEGV, sum = 0.0f;
    for (int s = tid; s < S; s += 256) {
        float v = __half2float(alpha[(size_t)s * Bc + b]) + final_logp[s];
        float nm = fmaxf(m, v);
        sum = sum * __expf(m - nm) + __expf(v - nm);
        m = nm;
    }
    __shared__ float mArr[256], sArr[256];
    mArr[tid] = m; sArr[tid] = sum;
    __syncthreads();
    for (int o = 128; o > 0; o >>= 1) {
        if (tid < o) {
            float m2 = mArr[tid + o], s2 = sArr[tid + o];
            float nm = fmaxf(mArr[tid], m2);
            sArr[tid] = sArr[tid] * __expf(mArr[tid] - nm) + s2 * __expf(m2 - nm);
            mArr[tid] = nm;
        }
        __syncthreads();
    }
    if (tid == 0) {
        float per = fmaxf(mArr[0], NEGV) + logf(sArr[0] + 1e-30f) + off[b];
        atomicAdd(out, per);
    }
}

// ---- fallback per-step kernel (no transpose buffer): logp from f32 [B][D] ----
__global__ void step_fallback_kernel(const __half* __restrict__ alpha_old,
                                     __half* __restrict__ alpha_new,
                                     const float* __restrict__ off_old,
                                     float* __restrict__ off_new,
                                     const float* __restrict__ logp_t,  // [B][D]
                                     const int* __restrict__ row_ptr,
                                     const uint2* __restrict__ arcs, int S) {
    const int wave = (blockIdx.x * blockDim.x + threadIdx.x) >> 6;
    const int lane = threadIdx.x & 63;
    if (wave >= S) return;
    const int lo = __builtin_amdgcn_readfirstlane(row_ptr[wave]);
    const int hi = __builtin_amdgcn_readfirstlane(row_ptr[wave + 1]);
    const float r0 = __half2float(alpha_old[0 * Bc + lane]);
    const float r1 = __half2float(alpha_old[1 * Bc + lane]);
    const float r2 = __half2float(alpha_old[2 * Bc + lane]);
    const float r3 = __half2float(alpha_old[3 * Bc + lane]);
    const float delta = fmaxf(fmaxf(r0, r1), fmaxf(r2, r3)) + DRIFT;
    float s0 = 0.0f;
    for (int i = lo; i < hi; ++i) {
        const uint2 A0 = arcs[i];
        const float w0 = __half2float(__ushort_as_half((unsigned short)(A0.y >> 16)));
        const float lp0 = logp_t[(size_t)lane * Dc + (A0.y & 0xffffu)];
        s0 += __expf(__half2float(alpha_old[(size_t)A0.x * Bc + lane]) + w0 + lp0);
    }
    const float r = __logf(s0 + 1e-30f);
    const float v = fminf(fmaxf(r - delta, CLAMP_LO), CLAMP_HI);
    alpha_new[(size_t)wave * Bc + lane] = __float2half(v);
    if (wave == 0) off_new[lane] = off_old[lane] + delta;
}

extern "C" void kernel_launch(void* const* d_in, const int* in_sizes, int n_in,
                              void* d_out, int out_size, void* d_ws, size_t ws_size,
                              hipStream_t stream) {
    const float* input      = (const float*)d_in[0];
    const float* arc_logw   = (const float*)d_in[1];
    const float* init_logp  = (const float*)d_in[2];
    const float* final_logp = (const float*)d_in[3];
    const int*   from_state = (const int*)d_in[4];
    const int*   to_state   = (const int*)d_in[5];
    const int*   pdf_id     = (const int*)d_in[6];
    const int S = in_sizes[2];
    const int A = in_sizes[4];

    char* ws = (char*)d_ws;
    size_t off = 0;
    auto alloc = [&](size_t bytes) -> char* {
        char* p = ws + off;
        off += (bytes + 255) & ~(size_t)255;
        return p;
    };

    const size_t need_small =
        2 * (((size_t)S * Bc * 2 + 255) & ~(size_t)255) +   // alphaA/B fp16
        (((size_t)A * 8 + 255) & ~(size_t)255) +            // packed arcs
        3 * (((size_t)(S + 1) * 4 + 255) & ~(size_t)255) +  // row_ptr/cursor/count
        4 * 256 + (NBLK + 64) * 4;                          // off bufs + barrier
    const size_t need_T = (size_t)Tc * Dc * Bc * 2 + 256;
    const bool do_persist = (ws_size >= need_small + need_T);

    __half* logpT = nullptr;
    if (do_persist) logpT = (__half*)alloc(need_T);
    __half* alphaA = (__half*)alloc((size_t)S * Bc * 2);
    __half* alphaB = (__half*)alloc((size_t)S * Bc * 2);
    float* offA    = (float*)alloc(Bc * 4);
    float* offB    = (float*)alloc(Bc * 4);
    int*   row_ptr = (int*)alloc((size_t)(S + 1) * 4);
    int*   cursor  = (int*)alloc((size_t)(S + 1) * 4);
    int*   count   = (int*)alloc((size_t)(S + 1) * 4);
    uint2* a_pack  = (uint2*)alloc((size_t)A * 8);
    int*   arrival = (int*)alloc((size_t)NBLK * 4);  // NBLK-1 used
    int*   gen     = (int*)alloc(256);

    hipMemsetAsync(count, 0, (size_t)S * 4, stream);
    hipMemsetAsync(offA, 0, Bc * 4, stream);
    hipMemsetAsync(arrival, 0, (size_t)NBLK * 4, stream);
    hipMemsetAsync(gen, 0, 256, stream);
    hipMemsetAsync(d_out, 0, sizeof(float), stream);

    if (do_persist) {
        dim3 tgrid(Dc / 64, Tc);
        transpose_kernel<<<tgrid, 256, 0, stream>>>(input, logpT);
    }
    init_alpha_kernel<<<(S * Bc + 255) / 256, 256, 0, stream>>>(init_logp, alphaA, S);
    hist_kernel<<<(A + 255) / 256, 256, 0, stream>>>(to_state, count, A);
    scan_kernel<<<1, 1024, 0, stream>>>(count, row_ptr, cursor, S);
    scatter_kernel<<<(A + 255) / 256, 256, 0, stream>>>(to_state, from_state, pdf_id,
                                                        arc_logw, cursor, a_pack, A);

    if (do_persist) {
        persist_kernel<<<NBLK, 256, 0, stream>>>(alphaA, alphaB, offA, logpT,
                                                 row_ptr, a_pack, S, Tc, arrival, gen);
        __half* finalA = (Tc & 1) ? alphaB : alphaA;
        final_reduce_kernel<<<Bc, 256, 0, stream>>>(finalA, offA, final_logp,
                                                    (float*)d_out, S);
    } else {
        __half* curA = alphaA;  __half* nxtA = alphaB;
        float*  curO = offA;    float*  nxtO = offB;
        const int step_blocks = (S + 3) / 4;
        for (int t = 0; t < Tc; ++t) {
            step_fallback_kernel<<<step_blocks, 256, 0, stream>>>(
                curA, nxtA, curO, nxtO, input + (size_t)t * Bc * Dc, row_ptr, a_pack, S);
            __half* ta = curA; curA = nxtA; nxtA = ta;
            float*  to_ = curO; curO = nxtO; nxtO = to_;
        }
        final_reduce_kernel<<<Bc, 256, 0, stream>>>(curA, curO, final_logp,
                                                    (float*)d_out, S);
    }
}

// Round 11
// 2059.667 us; speedup vs baseline: 19.2143x; 19.2143x over previous
//
#include <hip/hip_runtime.h>
#include <hip/hip_bf16.h>
#include <hip/hip_fp16.h>

#define NEGV (-1e30f)

constexpr int Bc = 64;    // batch == wave size
constexpr int Dc = 2048;  // pdf dim
constexpr int Tc = 150;   // time steps
constexpr float DRIFT = -5.0f;   // per-step drift guess; re-centering self-corrects
// Tight clamp so no-max exp accumulation cannot overflow:
// score = a + w + lp <= 40 + 0.5 + 0 = 40.5 ; exp(40.5)*13 ~ 5e18 << 3.4e38.
constexpr float CLAMP_LO = -60.0f, CLAMP_HI = 40.0f;

// ---- transpose input [T][B][D] f32 -> [T][D][B] fp16 ----
__global__ void transpose_kernel(const float* __restrict__ in, __half* __restrict__ out) {
    __shared__ float tile[64][65];
    const int t  = blockIdx.y;
    const int d0 = blockIdx.x * 64;
    const int lane = threadIdx.x & 63;
    const int w    = threadIdx.x >> 6;  // 0..3
    const float* inp = in + (size_t)t * Bc * Dc;
    #pragma unroll
    for (int b = w; b < 64; b += 4)
        tile[b][lane] = inp[(size_t)b * Dc + d0 + lane];
    __syncthreads();
    __half* outp = out + (size_t)t * Dc * Bc;
    #pragma unroll
    for (int d = w; d < 64; d += 4)
        outp[(size_t)(d0 + d) * Bc + lane] = __float2half(tile[lane][d]);
}

// ---- alpha_h[s][b] = init_logp[s] (fp16, clamped) ----
__global__ void init_alpha_kernel(const float* __restrict__ init_logp,
                                  __half* __restrict__ alpha_h, int S) {
    int idx  = blockIdx.x * blockDim.x + threadIdx.x;
    int wave = idx >> 6;
    int lane = threadIdx.x & 63;
    if (wave < S) {
        float v = fminf(fmaxf(init_logp[wave], CLAMP_LO), CLAMP_HI);
        alpha_h[(size_t)wave * Bc + lane] = __float2half(v);
    }
}

// ---- histogram of to_state ----
__global__ void hist_kernel(const int* __restrict__ to, int* __restrict__ count, int A) {
    int i = blockIdx.x * blockDim.x + threadIdx.x;
    if (i < A) atomicAdd(&count[to[i]], 1);
}

// ---- single-block exclusive scan -> row_ptr, cursor ----
__global__ void scan_kernel(const int* __restrict__ count, int* __restrict__ row_ptr,
                            int* __restrict__ cursor, int S) {
    __shared__ int lds[1024];
    const int tid = threadIdx.x;
    const int n = 1024;
    const int chunk = (S + n - 1) / n;
    const int lo = tid * chunk;
    const int hi = min(lo + chunk, S);
    int local = 0;
    for (int j = lo; j < hi; ++j) local += count[j];
    lds[tid] = local;
    __syncthreads();
    for (int off = 1; off < 1024; off <<= 1) {
        int add = (tid >= off) ? lds[tid - off] : 0;
        __syncthreads();
        lds[tid] += add;
        __syncthreads();
    }
    int excl = (tid > 0) ? lds[tid - 1] : 0;
    for (int j = lo; j < hi; ++j) {
        int c = count[j];
        row_ptr[j] = excl;
        cursor[j]  = excl;
        excl += c;
    }
    if (tid == n - 1) row_ptr[S] = lds[n - 1];
}

// ---- scatter arcs sorted by to_state, packed 8B: {f:u32, pdf:u16, w:fp16} ----
__global__ void scatter_kernel(const int* __restrict__ to, const int* __restrict__ from,
                               const int* __restrict__ pdf, const float* __restrict__ w,
                               int* __restrict__ cursor, uint2* __restrict__ a_pack, int A) {
    int i = blockIdx.x * blockDim.x + threadIdx.x;
    if (i >= A) return;
    int t = to[i];
    int p = atomicAdd(&cursor[t], 1);
    unsigned short wb = __half_as_ushort(__float2half(w[i]));
    a_pack[p] = make_uint2((unsigned)from[i],
                           ((unsigned)pdf[i] & 0xffffu) | ((unsigned)wb << 16));
}

// ---- one forward step: wave = state, lane = batch; NO-MAX exp accumulation ----
// XCD-contiguous swizzle: each XCD gets a contiguous state range so its arc
// slice + alpha writes are XCD-local and alpha/logp re-reads hit its L2.
// TR: logp_t is fp16 [D][B]. else: raw f32 input [B][D] (fallback).
template <bool TR>
__global__ void step_kernel(const __half* __restrict__ alpha_old,  // [S][B] fp16 stored
                            __half* __restrict__ alpha_new,        // [S][B] fp16 stored
                            const float* __restrict__ off_old,     // [B]
                            float* __restrict__ off_new,           // [B]
                            const void* __restrict__ logp_t,
                            const int* __restrict__ row_ptr,
                            const uint2* __restrict__ arcs, int S) {
    // bijective XCD swizzle (gridDim.x % 8 == 0 guaranteed by launcher padding)
    const int nb  = gridDim.x;
    const int cpx = nb >> 3;
    const int bid = blockIdx.x;
    const int swz = (nb % 8 == 0) ? ((bid & 7) * cpx + (bid >> 3)) : bid;
    const int wave = (swz * blockDim.x + threadIdx.x) >> 6;
    const int lane = threadIdx.x & 63;
    if (wave >= S) return;
    const int lo = __builtin_amdgcn_readfirstlane(row_ptr[wave]);
    const int hi = __builtin_amdgcn_readfirstlane(row_ptr[wave + 1]);
    const __half* lph = (const __half*)logp_t;
    const float*  lpf = (const float*)logp_t;

    // per-lane re-center reference: max stored alpha over states 0..3, plus
    // constant drift guess. Self-correcting across steps.
    const float r0 = __half2float(alpha_old[0 * Bc + lane]);
    const float r1 = __half2float(alpha_old[1 * Bc + lane]);
    const float r2 = __half2float(alpha_old[2 * Bc + lane]);
    const float r3 = __half2float(alpha_old[3 * Bc + lane]);
    const float delta = fmaxf(fmaxf(r0, r1), fmaxf(r2, r3)) + DRIFT;

    float s0 = 0.0f, s1 = 0.0f, s2 = 0.0f, s3 = 0.0f;
    int i = lo;
    for (; i + 3 < hi; i += 4) {
        const uint2 A0 = arcs[i],     A1 = arcs[i + 1];
        const uint2 A2 = arcs[i + 2], A3 = arcs[i + 3];
        const float w0 = __half2float(__ushort_as_half((unsigned short)(A0.y >> 16)));
        const float w1 = __half2float(__ushort_as_half((unsigned short)(A1.y >> 16)));
        const float w2 = __half2float(__ushort_as_half((unsigned short)(A2.y >> 16)));
        const float w3 = __half2float(__ushort_as_half((unsigned short)(A3.y >> 16)));
        const float lp0 = TR ? __half2float(lph[(size_t)(A0.y & 0xffffu) * Bc + lane])
                             : lpf[(size_t)lane * Dc + (A0.y & 0xffffu)];
        const float lp1 = TR ? __half2float(lph[(size_t)(A1.y & 0xffffu) * Bc + lane])
                             : lpf[(size_t)lane * Dc + (A1.y & 0xffffu)];
        const float lp2 = TR ? __half2float(lph[(size_t)(A2.y & 0xffffu) * Bc + lane])
                             : lpf[(size_t)lane * Dc + (A2.y & 0xffffu)];
        const float lp3 = TR ? __half2float(lph[(size_t)(A3.y & 0xffffu) * Bc + lane])
                             : lpf[(size_t)lane * Dc + (A3.y & 0xffffu)];
        const float a0 = __half2float(alpha_old[(size_t)A0.x * Bc + lane]);
        const float a1 = __half2float(alpha_old[(size_t)A1.x * Bc + lane]);
        const float a2 = __half2float(alpha_old[(size_t)A2.x * Bc + lane]);
        const float a3 = __half2float(alpha_old[(size_t)A3.x * Bc + lane]);
        s0 += __expf(a0 + w0 + lp0);
        s1 += __expf(a1 + w1 + lp1);
        s2 += __expf(a2 + w2 + lp2);
        s3 += __expf(a3 + w3 + lp3);
    }
    for (; i < hi; ++i) {
        const uint2 A0 = arcs[i];
        const float w0 = __half2float(__ushort_as_half((unsigned short)(A0.y >> 16)));
        const float lp0 = TR ? __half2float(lph[(size_t)(A0.y & 0xffffu) * Bc + lane])
                             : lpf[(size_t)lane * Dc + (A0.y & 0xffffu)];
        s0 += __expf(__half2float(alpha_old[(size_t)A0.x * Bc + lane]) + w0 + lp0);
    }
    const float r = __logf(((s0 + s1) + (s2 + s3)) + 1e-30f);
    const float v = fminf(fmaxf(r - delta, CLAMP_LO), CLAMP_HI);
    alpha_new[(size_t)wave * Bc + lane] = __float2half(v);
    if (wave == 0) off_new[lane] = off_old[lane] + delta;
}

// ---- final: per-batch logsumexp(stored + final_logp) + OFF[b], atomicAdd ----
__global__ void final_reduce_kernel(const __half* __restrict__ alpha,
                                    const float* __restrict__ off,
                                    const float* __restrict__ final_logp,
                                    float* __restrict__ out, int S) {
    const int b = blockIdx.x;     // 0..B-1
    const int tid = threadIdx.x;  // 256
    float m = NEGV, sum = 0.0f;
    for (int s = tid; s < S; s += 256) {
        float v = __half2float(alpha[(size_t)s * Bc + b]) + final_logp[s];
        float nm = fmaxf(m, v);
        sum = sum * __expf(m - nm) + __expf(v - nm);
        m = nm;
    }
    __shared__ float mArr[256], sArr[256];
    mArr[tid] = m; sArr[tid] = sum;
    __syncthreads();
    for (int o = 128; o > 0; o >>= 1) {
        if (tid < o) {
            float m2 = mArr[tid + o], s2 = sArr[tid + o];
            float nm = fmaxf(mArr[tid], m2);
            sArr[tid] = sArr[tid] * __expf(mArr[tid] - nm) + s2 * __expf(m2 - nm);
            mArr[tid] = nm;
        }
        __syncthreads();
    }
    if (tid == 0) {
        float per = fmaxf(mArr[0], NEGV) + logf(sArr[0] + 1e-30f) + off[b];
        atomicAdd(out, per);
    }
}

extern "C" void kernel_launch(void* const* d_in, const int* in_sizes, int n_in,
                              void* d_out, int out_size, void* d_ws, size_t ws_size,
                              hipStream_t stream) {
    const float* input      = (const float*)d_in[0];
    const float* arc_logw   = (const float*)d_in[1];
    const float* init_logp  = (const float*)d_in[2];
    const float* final_logp = (const float*)d_in[3];
    const int*   from_state = (const int*)d_in[4];
    const int*   to_state   = (const int*)d_in[5];
    const int*   pdf_id     = (const int*)d_in[6];
    const int S = in_sizes[2];
    const int A = in_sizes[4];

    char* ws = (char*)d_ws;
    size_t off = 0;
    auto alloc = [&](size_t bytes) -> char* {
        char* p = ws + off;
        off += (bytes + 255) & ~(size_t)255;
        return p;
    };

    const size_t need_small =
        2 * (((size_t)S * Bc * 2 + 255) & ~(size_t)255) +   // alphaA/B fp16
        (((size_t)A * 8 + 255) & ~(size_t)255) +            // packed arcs
        3 * (((size_t)(S + 1) * 4 + 255) & ~(size_t)255) +  // row_ptr/cursor/count
        2 * 256;                                            // offA/B
    const size_t need_T = (size_t)Tc * Dc * Bc * 2 + 256;
    const bool do_transpose = (ws_size >= need_small + need_T);

    __half* logpT = nullptr;
    if (do_transpose) logpT = (__half*)alloc(need_T);
    __half* alphaA = (__half*)alloc((size_t)S * Bc * 2);
    __half* alphaB = (__half*)alloc((size_t)S * Bc * 2);
    float* offA    = (float*)alloc(Bc * 4);
    float* offB    = (float*)alloc(Bc * 4);
    int*   row_ptr = (int*)alloc((size_t)(S + 1) * 4);
    int*   cursor  = (int*)alloc((size_t)(S + 1) * 4);
    int*   count   = (int*)alloc((size_t)(S + 1) * 4);
    uint2* a_pack  = (uint2*)alloc((size_t)A * 8);

    hipMemsetAsync(count, 0, (size_t)S * 4, stream);
    hipMemsetAsync(offA, 0, Bc * 4, stream);
    hipMemsetAsync(d_out, 0, sizeof(float), stream);

    if (do_transpose) {
        dim3 tgrid(Dc / 64, Tc);
        transpose_kernel<<<tgrid, 256, 0, stream>>>(input, logpT);
    }
    init_alpha_kernel<<<(S * Bc + 255) / 256, 256, 0, stream>>>(init_logp, alphaA, S);
    hist_kernel<<<(A + 255) / 256, 256, 0, stream>>>(to_state, count, A);
    scan_kernel<<<1, 1024, 0, stream>>>(count, row_ptr, cursor, S);
    scatter_kernel<<<(A + 255) / 256, 256, 0, stream>>>(to_state, from_state, pdf_id,
                                                        arc_logw, cursor, a_pack, A);

    __half* curA = alphaA;  __half* nxtA = alphaB;
    float*  curO = offA;    float*  nxtO = offB;
    // pad block count to a multiple of 8 so the XCD swizzle is bijective
    int step_blocks = (S + 3) / 4;                 // 4 states (waves) / 256-thr block
    step_blocks = (step_blocks + 7) & ~7;          // 5000 for S=20000
    for (int t = 0; t < Tc; ++t) {
        if (do_transpose) {
            step_kernel<true><<<step_blocks, 256, 0, stream>>>(
                curA, nxtA, curO, nxtO, logpT + (size_t)t * Dc * Bc, row_ptr, a_pack, S);
        } else {
            step_kernel<false><<<step_blocks, 256, 0, stream>>>(
                curA, nxtA, curO, nxtO, input + (size_t)t * Bc * Dc, row_ptr, a_pack, S);
        }
        __half* ta = curA; curA = nxtA; nxtA = ta;
        float*  to_ = curO; curO = nxtO; nxtO = to_;
    }
    final_reduce_kernel<<<Bc, 256, 0, stream>>>(curA, curO, final_logp, (float*)d_out, S);
}

// Round 12
// 2017.186 us; speedup vs baseline: 19.6189x; 1.0211x over previous
//
#include <hip/hip_runtime.h>
#include <hip/hip_bf16.h>
#include <hip/hip_fp16.h>

#define NEGV (-1e30f)

constexpr int Bc = 64;    // batch == wave size
constexpr int Dc = 2048;  // pdf dim
constexpr int Tc = 150;   // time steps
// exp-domain re-centering: stored EA ~ O(1..100); per-step rescale by
// e^{+5}/max(EA[0..3]) counters the ~-5 nat/step drift (self-correcting).
constexpr float EXP_NEG_DRIFT = 148.41316f;   // e^{5}
constexpr float STORE_CAP = 60000.0f;         // fp16 max 65504, keep headroom
constexpr float OFF_INIT = -10.0f;            // stored_init = exp(init_logp + 10)

// ---- transpose input [T][B][D] f32 -> E=exp(logp) [T][D][B] fp16 ----
__global__ void transpose_kernel(const float* __restrict__ in, __half* __restrict__ out) {
    __shared__ float tile[64][65];
    const int t  = blockIdx.y;
    const int d0 = blockIdx.x * 64;
    const int lane = threadIdx.x & 63;
    const int w    = threadIdx.x >> 6;  // 0..3
    const float* inp = in + (size_t)t * Bc * Dc;
    #pragma unroll
    for (int b = w; b < 64; b += 4)
        tile[b][lane] = inp[(size_t)b * Dc + d0 + lane];
    __syncthreads();
    __half* outp = out + (size_t)t * Dc * Bc;
    #pragma unroll
    for (int d = w; d < 64; d += 4)
        outp[(size_t)(d0 + d) * Bc + lane] = __float2half(__expf(tile[lane][d]));
}

// ---- EA[s][b] = exp(init_logp[s] - OFF_INIT); off[b] = OFF_INIT ----
__global__ void init_alpha_kernel(const float* __restrict__ init_logp,
                                  __half* __restrict__ alpha_h,
                                  float* __restrict__ off, int S) {
    int idx  = blockIdx.x * blockDim.x + threadIdx.x;
    int wave = idx >> 6;
    int lane = threadIdx.x & 63;
    if (wave < S) {
        float v = __expf(init_logp[wave] - OFF_INIT);
        alpha_h[(size_t)wave * Bc + lane] = __float2half(fminf(v, STORE_CAP));
    }
    if (idx < Bc) off[idx] = OFF_INIT;
}

// ---- histogram of to_state ----
__global__ void hist_kernel(const int* __restrict__ to, int* __restrict__ count, int A) {
    int i = blockIdx.x * blockDim.x + threadIdx.x;
    if (i < A) atomicAdd(&count[to[i]], 1);
}

// ---- single-block exclusive scan -> row_ptr, cursor ----
__global__ void scan_kernel(const int* __restrict__ count, int* __restrict__ row_ptr,
                            int* __restrict__ cursor, int S) {
    __shared__ int lds[1024];
    const int tid = threadIdx.x;
    const int n = 1024;
    const int chunk = (S + n - 1) / n;
    const int lo = tid * chunk;
    const int hi = min(lo + chunk, S);
    int local = 0;
    for (int j = lo; j < hi; ++j) local += count[j];
    lds[tid] = local;
    __syncthreads();
    for (int off = 1; off < 1024; off <<= 1) {
        int add = (tid >= off) ? lds[tid - off] : 0;
        __syncthreads();
        lds[tid] += add;
        __syncthreads();
    }
    int excl = (tid > 0) ? lds[tid - 1] : 0;
    for (int j = lo; j < hi; ++j) {
        int c = count[j];
        row_ptr[j] = excl;
        cursor[j]  = excl;
        excl += c;
    }
    if (tid == n - 1) row_ptr[S] = lds[n - 1];
}

// ---- scatter arcs sorted by to_state, packed 8B: {f:u32, pdf:u16, exp(w):fp16} ----
__global__ void scatter_kernel(const int* __restrict__ to, const int* __restrict__ from,
                               const int* __restrict__ pdf, const float* __restrict__ w,
                               int* __restrict__ cursor, uint2* __restrict__ a_pack, int A) {
    int i = blockIdx.x * blockDim.x + threadIdx.x;
    if (i >= A) return;
    int t = to[i];
    int p = atomicAdd(&cursor[t], 1);
    unsigned short wb = __half_as_ushort(__float2half(__expf(w[i])));
    a_pack[p] = make_uint2((unsigned)from[i],
                           ((unsigned)pdf[i] & 0xffffu) | ((unsigned)wb << 16));
}

// ---- one forward step, EXP DOMAIN: s = sum EA[f]*ew*E[p]; no transcendentals ----
// wave = state, lane = batch. XCD-contiguous swizzle for L2 locality.
// TR: E is fp16 [D][B]. else: raw f32 logp [B][D] (fallback, exp inline).
template <bool TR>
__global__ void step_kernel(const __half* __restrict__ alpha_old,  // [S][B] EA fp16
                            __half* __restrict__ alpha_new,        // [S][B] EA fp16
                            const float* __restrict__ off_old,     // [B]
                            float* __restrict__ off_new,           // [B]
                            const void* __restrict__ logp_t,
                            const int* __restrict__ row_ptr,
                            const uint2* __restrict__ arcs, int S) {
    const int nb  = gridDim.x;
    const int cpx = nb >> 3;
    const int bid = blockIdx.x;
    const int swz = (nb % 8 == 0) ? ((bid & 7) * cpx + (bid >> 3)) : bid;
    const int wave = (swz * blockDim.x + threadIdx.x) >> 6;
    const int lane = threadIdx.x & 63;
    if (wave >= S) return;
    const int lo = __builtin_amdgcn_readfirstlane(row_ptr[wave]);
    const int hi = __builtin_amdgcn_readfirstlane(row_ptr[wave + 1]);
    const __half* lph = (const __half*)logp_t;
    const float*  lpf = (const float*)logp_t;

    // multiplicative re-center reference from states 0..3 (self-correcting)
    const float r0 = __half2float(alpha_old[0 * Bc + lane]);
    const float r1 = __half2float(alpha_old[1 * Bc + lane]);
    const float r2 = __half2float(alpha_old[2 * Bc + lane]);
    const float r3 = __half2float(alpha_old[3 * Bc + lane]);
    const float dref = fmaxf(fmaxf(fmaxf(r0, r1), fmaxf(r2, r3)), 1e-20f);
    const float scale = EXP_NEG_DRIFT / dref;   // = exp(-delta)

    float s0 = 0.0f, s1 = 0.0f, s2 = 0.0f, s3 = 0.0f;
    int i = lo;
    for (; i + 3 < hi; i += 4) {
        const uint2 A0 = arcs[i],     A1 = arcs[i + 1];
        const uint2 A2 = arcs[i + 2], A3 = arcs[i + 3];
        const float w0 = __half2float(__ushort_as_half((unsigned short)(A0.y >> 16)));
        const float w1 = __half2float(__ushort_as_half((unsigned short)(A1.y >> 16)));
        const float w2 = __half2float(__ushort_as_half((unsigned short)(A2.y >> 16)));
        const float w3 = __half2float(__ushort_as_half((unsigned short)(A3.y >> 16)));
        const float e0 = TR ? __half2float(lph[(size_t)(A0.y & 0xffffu) * Bc + lane])
                            : __expf(lpf[(size_t)lane * Dc + (A0.y & 0xffffu)]);
        const float e1 = TR ? __half2float(lph[(size_t)(A1.y & 0xffffu) * Bc + lane])
                            : __expf(lpf[(size_t)lane * Dc + (A1.y & 0xffffu)]);
        const float e2 = TR ? __half2float(lph[(size_t)(A2.y & 0xffffu) * Bc + lane])
                            : __expf(lpf[(size_t)lane * Dc + (A2.y & 0xffffu)]);
        const float e3 = TR ? __half2float(lph[(size_t)(A3.y & 0xffffu) * Bc + lane])
                            : __expf(lpf[(size_t)lane * Dc + (A3.y & 0xffffu)]);
        const float a0 = __half2float(alpha_old[(size_t)A0.x * Bc + lane]);
        const float a1 = __half2float(alpha_old[(size_t)A1.x * Bc + lane]);
        const float a2 = __half2float(alpha_old[(size_t)A2.x * Bc + lane]);
        const float a3 = __half2float(alpha_old[(size_t)A3.x * Bc + lane]);
        s0 = fmaf(a0 * w0, e0, s0);
        s1 = fmaf(a1 * w1, e1, s1);
        s2 = fmaf(a2 * w2, e2, s2);
        s3 = fmaf(a3 * w3, e3, s3);
    }
    for (; i < hi; ++i) {
        const uint2 A0 = arcs[i];
        const float w0 = __half2float(__ushort_as_half((unsigned short)(A0.y >> 16)));
        const float e0 = TR ? __half2float(lph[(size_t)(A0.y & 0xffffu) * Bc + lane])
                            : __expf(lpf[(size_t)lane * Dc + (A0.y & 0xffffu)]);
        const float a0 = __half2float(alpha_old[(size_t)A0.x * Bc + lane]);
        s0 = fmaf(a0 * w0, e0, s0);
    }
    const float s = (s0 + s1) + (s2 + s3);
    alpha_new[(size_t)wave * Bc + lane] = __float2half(fminf(s * scale, STORE_CAP));
    if (wave == 0) off_new[lane] = off_old[lane] + (__logf(dref) - 5.0f);
}

// ---- final: per-batch logsumexp(log(EA) + final_logp) + OFF[b], atomicAdd ----
__global__ void final_reduce_kernel(const __half* __restrict__ alpha,
                                    const float* __restrict__ off,
                                    const float* __restrict__ final_logp,
                                    float* __restrict__ out, int S) {
    const int b = blockIdx.x;     // 0..B-1
    const int tid = threadIdx.x;  // 256
    float m = NEGV, sum = 0.0f;
    for (int s = tid; s < S; s += 256) {
        float ea = __half2float(alpha[(size_t)s * Bc + b]);
        float v = __logf(ea + 1e-35f) + final_logp[s];
        float nm = fmaxf(m, v);
        sum = sum * __expf(m - nm) + __expf(v - nm);
        m = nm;
    }
    __shared__ float mArr[256], sArr[256];
    mArr[tid] = m; sArr[tid] = sum;
    __syncthreads();
    for (int o = 128; o > 0; o >>= 1) {
        if (tid < o) {
            float m2 = mArr[tid + o], s2 = sArr[tid + o];
            float nm = fmaxf(mArr[tid], m2);
            sArr[tid] = sArr[tid] * __expf(mArr[tid] - nm) + s2 * __expf(m2 - nm);
            mArr[tid] = nm;
        }
        __syncthreads();
    }
    if (tid == 0) {
        float per = fmaxf(mArr[0], NEGV) + logf(sArr[0] + 1e-30f) + off[b];
        atomicAdd(out, per);
    }
}

extern "C" void kernel_launch(void* const* d_in, const int* in_sizes, int n_in,
                              void* d_out, int out_size, void* d_ws, size_t ws_size,
                              hipStream_t stream) {
    const float* input      = (const float*)d_in[0];
    const float* arc_logw   = (const float*)d_in[1];
    const float* init_logp  = (const float*)d_in[2];
    const float* final_logp = (const float*)d_in[3];
    const int*   from_state = (const int*)d_in[4];
    const int*   to_state   = (const int*)d_in[5];
    const int*   pdf_id     = (const int*)d_in[6];
    const int S = in_sizes[2];
    const int A = in_sizes[4];

    char* ws = (char*)d_ws;
    size_t off = 0;
    auto alloc = [&](size_t bytes) -> char* {
        char* p = ws + off;
        off += (bytes + 255) & ~(size_t)255;
        return p;
    };

    const size_t need_small =
        2 * (((size_t)S * Bc * 2 + 255) & ~(size_t)255) +   // alphaA/B fp16
        (((size_t)A * 8 + 255) & ~(size_t)255) +            // packed arcs
        3 * (((size_t)(S + 1) * 4 + 255) & ~(size_t)255) +  // row_ptr/cursor/count
        2 * 256;                                            // offA/B
    const size_t need_T = (size_t)Tc * Dc * Bc * 2 + 256;
    const bool do_transpose = (ws_size >= need_small + need_T);

    __half* logpT = nullptr;
    if (do_transpose) logpT = (__half*)alloc(need_T);
    __half* alphaA = (__half*)alloc((size_t)S * Bc * 2);
    __half* alphaB = (__half*)alloc((size_t)S * Bc * 2);
    float* offA    = (float*)alloc(Bc * 4);
    float* offB    = (float*)alloc(Bc * 4);
    int*   row_ptr = (int*)alloc((size_t)(S + 1) * 4);
    int*   cursor  = (int*)alloc((size_t)(S + 1) * 4);
    int*   count   = (int*)alloc((size_t)(S + 1) * 4);
    uint2* a_pack  = (uint2*)alloc((size_t)A * 8);

    hipMemsetAsync(count, 0, (size_t)S * 4, stream);
    hipMemsetAsync(d_out, 0, sizeof(float), stream);

    if (do_transpose) {
        dim3 tgrid(Dc / 64, Tc);
        transpose_kernel<<<tgrid, 256, 0, stream>>>(input, logpT);
    }
    init_alpha_kernel<<<(S * Bc + 255) / 256, 256, 0, stream>>>(init_logp, alphaA,
                                                                offA, S);
    hist_kernel<<<(A + 255) / 256, 256, 0, stream>>>(to_state, count, A);
    scan_kernel<<<1, 1024, 0, stream>>>(count, row_ptr, cursor, S);
    scatter_kernel<<<(A + 255) / 256, 256, 0, stream>>>(to_state, from_state, pdf_id,
                                                        arc_logw, cursor, a_pack, A);

    __half* curA = alphaA;  __half* nxtA = alphaB;
    float*  curO = offA;    float*  nxtO = offB;
    // 512-thread blocks: 8 states/block -> ~2500 blocks; pad to mult of 8 for
    // the bijective XCD swizzle.
    int step_blocks = (S + 7) / 8;
    step_blocks = (step_blocks + 7) & ~7;          // 2504 for S=20000
    for (int t = 0; t < Tc; ++t) {
        if (do_transpose) {
            step_kernel<true><<<step_blocks, 512, 0, stream>>>(
                curA, nxtA, curO, nxtO, logpT + (size_t)t * Dc * Bc, row_ptr, a_pack, S);
        } else {
            step_kernel<false><<<step_blocks, 512, 0, stream>>>(
                curA, nxtA, curO, nxtO, input + (size_t)t * Bc * Dc, row_ptr, a_pack, S);
        }
        __half* ta = curA; curA = nxtA; nxtA = ta;
        float*  to_ = curO; curO = nxtO; nxtO = to_;
    }
    final_reduce_kernel<<<Bc, 256, 0, stream>>>(curA, curO, final_logp, (float*)d_out, S);
}